// Round 2
// baseline (341.376 us; speedup 1.0000x reference)
//
#include <hip/hip_runtime.h>

#define HW   65536   // 256*256
#define HW4  16384   // HW/4
#define NC   256     // 64*4 planes per tensor
#define NB   64      // batch

typedef float vf4 __attribute__((ext_vector_type(4)));

// ---------------------------------------------------------------------------
// Kernel 1: partial plane sums. 2048 blocks = 512 planes x 4 quarters.
// Plane 0..255 = x, 256..511 = y. Each block sums 4096 float4 (1/4 plane).
// ---------------------------------------------------------------------------
__global__ void __launch_bounds__(256)
partial_sum_kernel(const float* __restrict__ x, const float* __restrict__ y,
                   float* __restrict__ partials) {
    const int blk   = blockIdx.x;           // 0..2047
    const int plane = blk >> 2;             // 0..511
    const int q     = blk & 3;              // quarter
    const float* src = (plane < NC) ? x : y;
    const int p = plane & (NC - 1);
    const vf4* base = (const vf4*)(src + (size_t)p * HW) + q * 4096;

    float s = 0.f;
    #pragma unroll
    for (int it = 0; it < 4; ++it) {
        int i = it * 1024 + threadIdx.x;
        vf4 v0 = base[i];
        vf4 v1 = base[i + 256];
        vf4 v2 = base[i + 512];
        vf4 v3 = base[i + 768];
        s += (v0.x + v0.y) + (v0.z + v0.w);
        s += (v1.x + v1.y) + (v1.z + v1.w);
        s += (v2.x + v2.y) + (v2.z + v2.w);
        s += (v3.x + v3.y) + (v3.z + v3.w);
    }
    #pragma unroll
    for (int off = 32; off > 0; off >>= 1)
        s += __shfl_down(s, off);
    __shared__ float ls[4];
    const int lane = threadIdx.x & 63, wv = threadIdx.x >> 6;
    if (lane == 0) ls[wv] = s;
    __syncthreads();
    if (threadIdx.x == 0)
        partials[blk] = (ls[0] + ls[1]) + (ls[2] + ls[3]);
}

// ---------------------------------------------------------------------------
// Kernel 2: fused gates + masked 1x1 convs. Each block recomputes its
// sample's 4 gates from the 32 partials (wave-uniform, ~1us amortized);
// this removes the 1-block gates dispatch and its launch gap.
// Plain stores (NOT nontemporal): fill kernel proves plain stores sustain
// 6.6 TB/s, and L2/L3 can absorb part of the 201 MB so drain overlaps
// past kernel end. Gate arithmetic order matches the old gates_kernel
// exactly (bitwise-identical threshold decisions).
// ---------------------------------------------------------------------------
__global__ void __launch_bounds__(256)
main_kernel(const float* __restrict__ x, const float* __restrict__ y,
            const float* __restrict__ partials,
            const float* __restrict__ w1, const float* __restrict__ b1,
            const float* __restrict__ w2, const float* __restrict__ b2,
            const float* __restrict__ we1, const float* __restrict__ be1,
            const float* __restrict__ we2, const float* __restrict__ be2,
            const float* __restrict__ we3, const float* __restrict__ be3,
            const float* __restrict__ we4, const float* __restrict__ be4,
            float* __restrict__ outx, float* __restrict__ outy) {
    const int blk   = blockIdx.x;
    const int n     = blk >> 6;
    const int chunk = blk & 63;
    const int hw4   = chunk * 256 + threadIdx.x;      // float4 index in plane

    // ---- gates (recomputed per block; wave-uniform) ----
    const float inv = 1.0f / (float)HW;
    float g[2][2];
    #pragma unroll
    for (int t = 0; t < 2; ++t) {
        float p[4];
        #pragma unroll
        for (int c = 0; c < 4; ++c) {
            const float* pp = partials + (t * NC + n * 4 + c) * 4;
            p[c] = ((pp[0] + pp[1]) + (pp[2] + pp[3])) * inv;
        }
        float h0 = w1[0]*p[0] + w1[1]*p[1] + w1[2]*p[2] + w1[3]*p[3] + b1[0];
        float h1 = w1[4]*p[0] + w1[5]*p[1] + w1[6]*p[2] + w1[7]*p[3] + b1[1];
        g[t][0] = w2[0]*h0 + w2[1]*h1 + b2[0];
        g[t][1] = w2[2]*h0 + w2[3]*h1 + b2[1];
    }
    const float mx0 = g[0][0] > 0.f ? 1.f : 0.f;
    const float mx1 = g[0][1] > 0.f ? 1.f : 0.f;
    const float my0 = g[1][0] > 0.f ? 1.f : 0.f;
    const float my1 = g[1][1] > 0.f ? 1.f : 0.f;

    // ---- masked 1x1 convs ----
    const vf4* xb = (const vf4*)(x + (size_t)n * 4 * HW);
    const vf4* yb = (const vf4*)(y + (size_t)n * 4 * HW);

    vf4 xv[4], yv[4];
    #pragma unroll
    for (int c = 0; c < 4; ++c) {
        xv[c] = xb[c * HW4 + hw4];
        yv[c] = yb[c * HW4 + hw4];
    }

    // out_x: 4 channels = mx0*conv(x, we1) + my0*conv(y, we3)
    vf4* ox = (vf4*)(outx + (size_t)n * 4 * HW);
    #pragma unroll
    for (int o = 0; o < 4; ++o) {
        const float bb = mx0 * be1[o] + my0 * be3[o];
        vf4 a = {bb, bb, bb, bb};
        #pragma unroll
        for (int c = 0; c < 4; ++c) {
            const float wx = mx0 * we1[o * 4 + c];
            const float wy = my0 * we3[o * 4 + c];
            a += wx * xv[c] + wy * yv[c];
        }
        ox[o * HW4 + hw4] = a;
    }

    // out_y: 8 channels = mx1*conv(x, we2) + my1*conv(y, we4)
    vf4* oy = (vf4*)(outy + (size_t)n * 8 * HW);
    #pragma unroll
    for (int o = 0; o < 8; ++o) {
        const float bb = mx1 * be2[o] + my1 * be4[o];
        vf4 a = {bb, bb, bb, bb};
        #pragma unroll
        for (int c = 0; c < 4; ++c) {
            const float wx = mx1 * we2[o * 4 + c];
            const float wy = my1 * we4[o * 4 + c];
            a += wx * xv[c] + wy * yv[c];
        }
        oy[o * HW4 + hw4] = a;
    }
}

extern "C" void kernel_launch(void* const* d_in, const int* in_sizes, int n_in,
                              void* d_out, int out_size, void* d_ws, size_t ws_size,
                              hipStream_t stream) {
    const float* x     = (const float*)d_in[0];
    const float* y     = (const float*)d_in[1];
    const float* w_rf1 = (const float*)d_in[2];
    const float* b_rf1 = (const float*)d_in[3];
    const float* w_rf2 = (const float*)d_in[4];
    const float* b_rf2 = (const float*)d_in[5];
    const float* w_e1  = (const float*)d_in[6];
    const float* b_e1  = (const float*)d_in[7];
    const float* w_e2  = (const float*)d_in[8];
    const float* b_e2  = (const float*)d_in[9];
    const float* w_e3  = (const float*)d_in[10];
    const float* b_e3  = (const float*)d_in[11];
    const float* w_e4  = (const float*)d_in[12];
    const float* b_e4  = (const float*)d_in[13];

    float* ws       = (float*)d_ws;
    float* partials = ws;           // 2048 floats

    float* outx = (float*)d_out;                          // [64,4,256,256]
    float* outy = outx + (size_t)NB * 4 * HW;             // [64,8,256,256]

    hipLaunchKernelGGL(partial_sum_kernel, dim3(2048), dim3(256), 0, stream,
                       x, y, partials);
    hipLaunchKernelGGL(main_kernel, dim3(4096), dim3(256), 0, stream,
                       x, y, partials,
                       w_rf1, b_rf1, w_rf2, b_rf2,
                       w_e1, b_e1, w_e2, b_e2, w_e3, b_e3, w_e4, b_e4,
                       outx, outy);
}

// Round 3
// 330.467 us; speedup vs baseline: 1.0330x; 1.0330x over previous
//
#include <hip/hip_runtime.h>

#define HW   65536   // 256*256
#define HW4  16384   // HW/4
#define NC   256     // 64*4 planes per tensor
#define NB   64      // batch

typedef float vf4 __attribute__((ext_vector_type(4)));

// ---------------------------------------------------------------------------
// Kernel 1: partial plane sums. 2048 blocks = 512 planes x 4 quarters.
// Plane 0..255 = x, 256..511 = y. Each block sums 4096 float4 (1/4 plane).
// Side effect we rely on: warms x,y into L3 (134 MB < 256 MB) for kernel 2.
// ---------------------------------------------------------------------------
__global__ void __launch_bounds__(256)
partial_sum_kernel(const float* __restrict__ x, const float* __restrict__ y,
                   float* __restrict__ partials) {
    const int blk   = blockIdx.x;           // 0..2047
    const int plane = blk >> 2;             // 0..511
    const int q     = blk & 3;              // quarter
    const float* src = (plane < NC) ? x : y;
    const int p = plane & (NC - 1);
    const vf4* base = (const vf4*)(src + (size_t)p * HW) + q * 4096;

    float s = 0.f;
    #pragma unroll
    for (int it = 0; it < 4; ++it) {
        int i = it * 1024 + threadIdx.x;
        vf4 v0 = base[i];
        vf4 v1 = base[i + 256];
        vf4 v2 = base[i + 512];
        vf4 v3 = base[i + 768];
        s += (v0.x + v0.y) + (v0.z + v0.w);
        s += (v1.x + v1.y) + (v1.z + v1.w);
        s += (v2.x + v2.y) + (v2.z + v2.w);
        s += (v3.x + v3.y) + (v3.z + v3.w);
    }
    #pragma unroll
    for (int off = 32; off > 0; off >>= 1)
        s += __shfl_down(s, off);
    __shared__ float ls[4];
    const int lane = threadIdx.x & 63, wv = threadIdx.x >> 6;
    if (lane == 0) ls[wv] = s;
    __syncthreads();
    if (threadIdx.x == 0)
        partials[blk] = (ls[0] + ls[1]) + (ls[2] + ls[3]);
}

// ---------------------------------------------------------------------------
// Kernel 2: fused gates + masked 1x1 convs.
// - Gates recomputed per block from the 32 partials (wave-uniform, L2-hit).
// - NT stores: bypass L2/L3 so the 201 MB output stream does NOT evict the
//   L3-resident x,y (this was R2's -7us regression when removed).
// - Block-uniform skip: x-planes only read if (mx0|mx1), y if (my0|my1).
//   Exact: skipped operand contributes 0 to every output.
// ---------------------------------------------------------------------------
__global__ void __launch_bounds__(256)
main_kernel(const float* __restrict__ x, const float* __restrict__ y,
            const float* __restrict__ partials,
            const float* __restrict__ w1, const float* __restrict__ b1,
            const float* __restrict__ w2, const float* __restrict__ b2,
            const float* __restrict__ we1, const float* __restrict__ be1,
            const float* __restrict__ we2, const float* __restrict__ be2,
            const float* __restrict__ we3, const float* __restrict__ be3,
            const float* __restrict__ we4, const float* __restrict__ be4,
            float* __restrict__ outx, float* __restrict__ outy) {
    const int blk   = blockIdx.x;
    const int n     = blk >> 6;
    const int chunk = blk & 63;
    const int hw4   = chunk * 256 + threadIdx.x;      // float4 index in plane

    // ---- gates (recomputed per block; wave-uniform) ----
    const float inv = 1.0f / (float)HW;
    float g[2][2];
    #pragma unroll
    for (int t = 0; t < 2; ++t) {
        float p[4];
        #pragma unroll
        for (int c = 0; c < 4; ++c) {
            const float* pp = partials + (t * NC + n * 4 + c) * 4;
            p[c] = ((pp[0] + pp[1]) + (pp[2] + pp[3])) * inv;
        }
        float h0 = w1[0]*p[0] + w1[1]*p[1] + w1[2]*p[2] + w1[3]*p[3] + b1[0];
        float h1 = w1[4]*p[0] + w1[5]*p[1] + w1[6]*p[2] + w1[7]*p[3] + b1[1];
        g[t][0] = w2[0]*h0 + w2[1]*h1 + b2[0];
        g[t][1] = w2[2]*h0 + w2[3]*h1 + b2[1];
    }
    const float mx0 = g[0][0] > 0.f ? 1.f : 0.f;
    const float mx1 = g[0][1] > 0.f ? 1.f : 0.f;
    const float my0 = g[1][0] > 0.f ? 1.f : 0.f;
    const float my1 = g[1][1] > 0.f ? 1.f : 0.f;

    // ---- masked 1x1 convs ----
    const vf4* xb = (const vf4*)(x + (size_t)n * 4 * HW);
    const vf4* yb = (const vf4*)(y + (size_t)n * 4 * HW);

    vf4 xv[4] = {}, yv[4] = {};
    if (mx0 + mx1 > 0.f) {           // block-uniform: x needed at all?
        #pragma unroll
        for (int c = 0; c < 4; ++c) xv[c] = xb[c * HW4 + hw4];
    }
    if (my0 + my1 > 0.f) {           // block-uniform: y needed at all?
        #pragma unroll
        for (int c = 0; c < 4; ++c) yv[c] = yb[c * HW4 + hw4];
    }

    // out_x: 4 channels = mx0*conv(x, we1) + my0*conv(y, we3)
    vf4* ox = (vf4*)(outx + (size_t)n * 4 * HW);
    #pragma unroll
    for (int o = 0; o < 4; ++o) {
        const float bb = mx0 * be1[o] + my0 * be3[o];
        vf4 a = {bb, bb, bb, bb};
        #pragma unroll
        for (int c = 0; c < 4; ++c) {
            const float wx = mx0 * we1[o * 4 + c];
            const float wy = my0 * we3[o * 4 + c];
            a += wx * xv[c] + wy * yv[c];
        }
        __builtin_nontemporal_store(a, &ox[o * HW4 + hw4]);
    }

    // out_y: 8 channels = mx1*conv(x, we2) + my1*conv(y, we4)
    vf4* oy = (vf4*)(outy + (size_t)n * 8 * HW);
    #pragma unroll
    for (int o = 0; o < 8; ++o) {
        const float bb = mx1 * be2[o] + my1 * be4[o];
        vf4 a = {bb, bb, bb, bb};
        #pragma unroll
        for (int c = 0; c < 4; ++c) {
            const float wx = mx1 * we2[o * 4 + c];
            const float wy = my1 * we4[o * 4 + c];
            a += wx * xv[c] + wy * yv[c];
        }
        __builtin_nontemporal_store(a, &oy[o * HW4 + hw4]);
    }
}

extern "C" void kernel_launch(void* const* d_in, const int* in_sizes, int n_in,
                              void* d_out, int out_size, void* d_ws, size_t ws_size,
                              hipStream_t stream) {
    const float* x     = (const float*)d_in[0];
    const float* y     = (const float*)d_in[1];
    const float* w_rf1 = (const float*)d_in[2];
    const float* b_rf1 = (const float*)d_in[3];
    const float* w_rf2 = (const float*)d_in[4];
    const float* b_rf2 = (const float*)d_in[5];
    const float* w_e1  = (const float*)d_in[6];
    const float* b_e1  = (const float*)d_in[7];
    const float* w_e2  = (const float*)d_in[8];
    const float* b_e2  = (const float*)d_in[9];
    const float* w_e3  = (const float*)d_in[10];
    const float* b_e3  = (const float*)d_in[11];
    const float* w_e4  = (const float*)d_in[12];
    const float* b_e4  = (const float*)d_in[13];

    float* ws       = (float*)d_ws;
    float* partials = ws;           // 2048 floats

    float* outx = (float*)d_out;                          // [64,4,256,256]
    float* outy = outx + (size_t)NB * 4 * HW;             // [64,8,256,256]

    hipLaunchKernelGGL(partial_sum_kernel, dim3(2048), dim3(256), 0, stream,
                       x, y, partials);
    hipLaunchKernelGGL(main_kernel, dim3(4096), dim3(256), 0, stream,
                       x, y, partials,
                       w_rf1, b_rf1, w_rf2, b_rf2,
                       w_e1, b_e1, w_e2, b_e2, w_e3, b_e3, w_e4, b_e4,
                       outx, outy);
}